// Round 3
// baseline (454.314 us; speedup 1.0000x reference)
//
#include <hip/hip_runtime.h>
#include <hip/hip_bf16.h>
#include <cstdint>
#include <cstddef>

// ---------- constants ----------
#define BATCH 2
#define CTX 2048
#define EMB 2048
#define NH 16
#define NG 4
#define HD 128
#define NQK (EMB + 2*NG*HD)   // 3072 combined QKV output cols
#define MROWS (BATCH*CTX)     // 4096

typedef __bf16 bf16x8 __attribute__((ext_vector_type(8)));
typedef float  f32x4  __attribute__((ext_vector_type(4)));
typedef float  f32x16 __attribute__((ext_vector_type(16)));

__device__ __forceinline__ ushort f2bf(float f) {
    uint32_t u = __float_as_uint(f);
    u += 0x7FFFu + ((u >> 16) & 1u);   // round-to-nearest-even
    return (ushort)(u >> 16);
}

__device__ __forceinline__ uint32_t packbf(float a, float b) {
    ushort lo = __builtin_bit_cast(ushort, (__bf16)a);
    ushort hi = __builtin_bit_cast(ushort, (__bf16)b);
    return (uint32_t)lo | ((uint32_t)hi << 16);
}

__device__ __forceinline__ bf16x8 mkfrag(uint32_t a, uint32_t b, uint32_t c, uint32_t d) {
    union { uint32_t u[4]; bf16x8 v; } z;
    z.u[0] = a; z.u[1] = b; z.u[2] = c; z.u[3] = d;
    return z.v;
}

__device__ __forceinline__ void gload_lds16(const void* g, void* l) {
    __builtin_amdgcn_global_load_lds((const __attribute__((address_space(1))) void*)g,
                                     (__attribute__((address_space(3))) void*)l, 16, 0, 0);
}

// ---------- sin table: sintab[pos][j], j in 0..63 ----------
__global__ __launch_bounds__(256) void k_sintab(float* __restrict__ sintab) {
    int t = blockIdx.x * 256 + threadIdx.x;   // 2048*64
    int j = t & 63, p = t >> 6;
    float theta = 1.0f / powf(10000.0f, (float)(2 * j) / 64.0f);
    sintab[t] = sinf((float)p * theta);
}

// ---------- f32 -> bf16 elementwise (4 per thread) ----------
__global__ __launch_bounds__(256) void k_cvt(const float4* __restrict__ src, ushort4* __restrict__ dst) {
    int i = blockIdx.x * 256 + threadIdx.x;
    float4 v = src[i];
    ushort4 o;
    o.x = f2bf(v.x); o.y = f2bf(v.y); o.z = f2bf(v.z); o.w = f2bf(v.w);
    dst[i] = o;
}

// ---------- tiled transpose f32[R][C] -> bf16 dst[C][R] ----------
__global__ __launch_bounds__(256) void k_transpose_cvt(const float* __restrict__ src, int src_ld,
                                                       ushort* __restrict__ dst, int dst_ld) {
    __shared__ float tile[32][33];
    int tx = threadIdx.x, ty = threadIdx.y;          // 32 x 8
    int c0 = blockIdx.x * 32, r0 = blockIdx.y * 32;
    #pragma unroll
    for (int i = 0; i < 4; ++i)
        tile[ty + i*8][tx] = src[(size_t)(r0 + ty + i*8) * src_ld + c0 + tx];
    __syncthreads();
    #pragma unroll
    for (int i = 0; i < 4; ++i)
        dst[(size_t)(c0 + ty + i*8) * dst_ld + r0 + tx] = f2bf(tile[tx][ty + i*8]);
}

// ---------- RoPE + convert (+ optional scale folded in) ----------
__global__ __launch_bounds__(256) void k_rope_cvt(const float* __restrict__ qkv, int ld, int co, int nh,
                                                  const float* __restrict__ sintab, ushort* __restrict__ out,
                                                  float qs) {
    int t = blockIdx.x * 256 + threadIdx.x;   // BATCH*nh*CTX*64
    int j = t & 63;
    int rest = t >> 6;
    int pos = rest & (CTX - 1);
    int rest2 = rest >> 11;
    int hh = rest2 % nh;
    int b = rest2 / nh;
    const float* base = qkv + (size_t)(b * CTX + pos) * ld + co + hh * HD;
    float a = base[j];
    float bb = base[j + 64];
    float sv = sintab[pos * 64 + j] * qs;
    ushort* ob = out + ((size_t)((b * nh + hh) * CTX + pos)) * HD;
    ob[j]      = f2bf((a - bb) * sv);
    ob[j + 64] = f2bf((bb + a) * sv);
}

// ---------- GEMM: C[M][N] (f32) = A[M][K] (bf16) x Bt[N][K] (bf16), optional bias ----------
__global__ __launch_bounds__(256) void k_gemm_bt(const ushort* __restrict__ A, const ushort* __restrict__ Bt,
                                                 float* __restrict__ C, int M, int N, int K,
                                                 const float* __restrict__ bias) {
    __shared__ __align__(16) ushort As[128 * 32];
    __shared__ __align__(16) ushort Bs[128 * 32];
    int tid = threadIdx.x;
    int lane = tid & 63;
    int wave = tid >> 6;
    int wr = wave >> 1, wc = wave & 1;
    int m0 = blockIdx.y * 128, n0 = blockIdx.x * 128;
    int lr = lane & 15, lg = lane >> 4;

    f32x4 acc[4][4] = {};

    int arow = lane >> 2;        // 0..15 within chunk
    int kpart = (lane & 3) * 8;  // 0,8,16,24

    for (int k0 = 0; k0 < K; k0 += 32) {
        #pragma unroll
        for (int s = 0; s < 2; ++s) {
            int c = wave * 2 + s;
            const ushort* ga = A + (size_t)(m0 + c*16 + arow) * K + k0 + kpart;
            gload_lds16(ga, &As[c * 512]);
            const ushort* gb = Bt + (size_t)(n0 + c*16 + arow) * K + k0 + kpart;
            gload_lds16(gb, &Bs[c * 512]);
        }
        __syncthreads();
        bf16x8 af[4], bfr[4];
        #pragma unroll
        for (int mt = 0; mt < 4; ++mt)
            af[mt] = *(const bf16x8*)&As[(wr*64 + mt*16 + lr) * 32 + lg * 8];
        #pragma unroll
        for (int nt = 0; nt < 4; ++nt)
            bfr[nt] = *(const bf16x8*)&Bs[(wc*64 + nt*16 + lr) * 32 + lg * 8];
        #pragma unroll
        for (int mt = 0; mt < 4; ++mt)
            #pragma unroll
            for (int nt = 0; nt < 4; ++nt)
                acc[mt][nt] = __builtin_amdgcn_mfma_f32_16x16x32_bf16(af[mt], bfr[nt], acc[mt][nt], 0, 0, 0);
        __syncthreads();
    }

    #pragma unroll
    for (int mt = 0; mt < 4; ++mt) {
        #pragma unroll
        for (int nt = 0; nt < 4; ++nt) {
            int col = n0 + wc*64 + nt*16 + lr;
            float bv = bias ? bias[col] : 0.0f;
            #pragma unroll
            for (int r = 0; r < 4; ++r) {
                int row = m0 + wr*64 + mt*16 + lg*4 + r;
                C[(size_t)row * N + col] = acc[mt][nt][r] + bv;
            }
        }
    }
}

// ---------- flash attention v3: 2-wave split-KV blocks, 32 q-rows / block ----------
// Qb [B][NH][CTX][HD] (pre-scaled by 1/sqrt(128)*log2(e)), Kb [B][NG][CTX][HD], Vt [B][NG][HD][CTX]
// y [B*CTX][NH*HD] bf16
// Block B: q-tile t = 63-(B>>5), head bh = B&31. Wave w in {0,1} takes kv-steps w, w+2, ...
// Private (m,l,O) per wave; merged via LDS at the end.
__global__ __launch_bounds__(128, 4) void k_attn3(const ushort* __restrict__ Qb, const ushort* __restrict__ Kb,
                                                  const ushort* __restrict__ Vt, ushort* __restrict__ y) {
    __shared__ __align__(16) float sOd[32][128];
    __shared__ float sm[32], sl[32];
    int lane = threadIdx.x & 63;
    int w    = threadIdx.x >> 6;   // 0 or 1
    int B  = blockIdx.x;
    int t  = 63 - (B >> 5);        // q-tile index, 0..63 (longest first)
    int bh = B & 31;
    int b = bh >> 4, h = bh & 15, g = h >> 2;
    int ln = lane & 31, hi = lane >> 5;
    int q0 = t * 32;

    // Q fragments: B-operand, col = ln = q row, k(hd) = s*16 + hi*8 + e
    const ushort* qrow = Qb + ((size_t)((b*NH + h) * CTX) + q0 + ln) * HD + hi * 8;
    bf16x8 qf[8];
    #pragma unroll
    for (int s = 0; s < 8; ++s) qf[s] = *(const bf16x8*)(qrow + s * 16);

    const ushort* kbase = Kb + (size_t)(b*NG + g) * CTX * HD;
    const ushort* vbase = Vt + (size_t)(b*NG + g) * HD * CTX;

    f32x16 od[4] = {};             // O: row q = (r&3)+8*(r>>2)+4*hi, col d = dt*32+ln
    float m = -1e30f, lsum = 0.0f; // per q = ln (lanes l and l^32 hold same q)

    int nsteps = t + 1;
    for (int si = w; si < nsteps; si += 2) {
        int kv0 = si * 32;
        // S^T = K_tile . Q_tile^T  (rows = kv, cols = q); two acc chains for ILP
        f32x16 st0 = {}, st1 = {};
        const ushort* kp = kbase + ((size_t)(kv0 + ln)) * HD + hi * 8;
        #pragma unroll
        for (int s = 0; s < 4; ++s) {
            bf16x8 kfa = *(const bf16x8*)(kp + (2*s) * 16);
            bf16x8 kfb = *(const bf16x8*)(kp + (2*s+1) * 16);
            st0 = __builtin_amdgcn_mfma_f32_32x32x16_bf16(kfa, qf[2*s],   st0, 0, 0, 0);
            st1 = __builtin_amdgcn_mfma_f32_32x32x16_bf16(kfb, qf[2*s+1], st1, 0, 0, 0);
        }
        f32x16 st = st0 + st1;
        // V fragments for this kv tile (issue loads early)
        bf16x8 vf[8];
        #pragma unroll
        for (int dt = 0; dt < 4; ++dt)
            #pragma unroll
            for (int ks = 0; ks < 2; ++ks)
                vf[dt*2 + ks] = *(const bf16x8*)(vbase + (size_t)(dt*32 + ln) * CTX + kv0 + ks*16 + hi*8);

        // causal mask — only the diagonal tile
        if (kv0 == q0) {
            #pragma unroll
            for (int r = 0; r < 16; ++r) {
                int kl = (r & 3) + 8*(r >> 2) + 4*hi;
                if (kl > ln) st[r] = -1e30f;
            }
        }
        // tile max: tree reduce in-register + one cross-half exchange
        float m8[8];
        #pragma unroll
        for (int r = 0; r < 8; ++r) m8[r] = fmaxf(st[r], st[r+8]);
        #pragma unroll
        for (int r = 0; r < 4; ++r) m8[r] = fmaxf(m8[r], m8[r+4]);
        float pmax = fmaxf(fmaxf(m8[0], m8[1]), fmaxf(m8[2], m8[3]));
        pmax = fmaxf(pmax, __shfl_xor(pmax, 32, 64));

        // defer-max: rescale O only when the running max grows by > 8 (log2 domain)
        if (!__all(pmax <= m + 8.0f)) {
            float mnew = fmaxf(m, pmax);
            float alpha = exp2f(m - mnew);
            lsum *= alpha;
            m = mnew;
            #pragma unroll
            for (int r = 0; r < 16; ++r) {
                float ar = __shfl(alpha, (r & 3) + 8*(r >> 2) + 4*hi, 64);
                #pragma unroll
                for (int dt = 0; dt < 4; ++dt) od[dt][r] *= ar;
            }
        }
        // P = exp2(S - m), row sum
        float p[16];
        float ls = 0.0f;
        #pragma unroll
        for (int r = 0; r < 16; ++r) { p[r] = exp2f(st[r] - m); ls += p[r]; }
        lsum += ls + __shfl_xor(ls, 32, 64);

        // pack P to bf16 pairs and redistribute into PV A-fragment layout
        uint32_t wp[8], xp[8];
        #pragma unroll
        for (int j = 0; j < 8; ++j) wp[j] = packbf(p[2*j], p[2*j + 1]);
        #pragma unroll
        for (int j = 0; j < 8; ++j) xp[j] = (uint32_t)__shfl_xor((int)wp[j], 32, 64);
        bf16x8 pa0 = hi ? mkfrag(xp[2], xp[3], wp[2], wp[3]) : mkfrag(wp[0], wp[1], xp[0], xp[1]);
        bf16x8 pa1 = hi ? mkfrag(xp[6], xp[7], wp[6], wp[7]) : mkfrag(wp[4], wp[5], xp[4], xp[5]);

        // O += P . V  (4 independent d-tile chains)
        #pragma unroll
        for (int dt = 0; dt < 4; ++dt) {
            od[dt] = __builtin_amdgcn_mfma_f32_32x32x16_bf16(pa0, vf[dt*2 + 0], od[dt], 0, 0, 0);
            od[dt] = __builtin_amdgcn_mfma_f32_32x32x16_bf16(pa1, vf[dt*2 + 1], od[dt], 0, 0, 0);
        }
    }

    // ---- merge the two waves' partials ----
    if (w == 1) {
        #pragma unroll
        for (int r = 0; r < 16; ++r) {
            int ri = (r & 3) + 8*(r >> 2) + 4*hi;
            #pragma unroll
            for (int dt = 0; dt < 4; ++dt) sOd[ri][dt*32 + ln] = od[dt][r];
        }
        if (hi == 0) { sm[ln] = m; sl[ln] = lsum; }
    }
    __syncthreads();
    if (w == 0) {
        float m1 = sm[ln], l1 = sl[ln];
        float mnew = fmaxf(m, m1);
        float a0 = exp2f(m - mnew);
        float a1 = exp2f(m1 - mnew);
        float inv = 1.0f / (lsum * a0 + l1 * a1);
        #pragma unroll
        for (int r = 0; r < 16; ++r) {
            int ri = (r & 3) + 8*(r >> 2) + 4*hi;
            float a0r = __shfl(a0, ri, 64);
            float a1r = __shfl(a1, ri, 64);
            float ivr = __shfl(inv, ri, 64);
            int row = q0 + ri;
            #pragma unroll
            for (int dt = 0; dt < 4; ++dt) {
                float v = (od[dt][r] * a0r + sOd[ri][dt*32 + ln] * a1r) * ivr;
                y[((size_t)(b*CTX + row)) * (NH*HD) + h*HD + dt*32 + ln] = f2bf(v);
            }
        }
    }
}

// ---------- workspace layout (bytes) ----------
#define SIN_OFF   ((size_t)0)
#define XB_OFF    ((size_t)524288)
#define WT_OFF    ((size_t)17301504)
#define WOT_OFF   ((size_t)29884416)
#define QKV_OFF   ((size_t)38273024)
#define QB_OFF    ((size_t)88604672)
#define KB_OFF    ((size_t)105381888)
#define VT_OFF    ((size_t)109576192)
#define YB_OFF    ((size_t)113770496)

extern "C" void kernel_launch(void* const* d_in, const int* in_sizes, int n_in,
                              void* d_out, int out_size, void* d_ws, size_t ws_size,
                              hipStream_t stream) {
    const float* x  = (const float*)d_in[0];
    const float* Wq = (const float*)d_in[1];
    const float* Wk = (const float*)d_in[2];
    const float* Wv = (const float*)d_in[3];
    const float* Wo = (const float*)d_in[4];
    const float* bo = (const float*)d_in[5];
    float* out = (float*)d_out;
    char* ws = (char*)d_ws;

    float*  sintab = (float*)(ws + SIN_OFF);
    ushort* xb     = (ushort*)(ws + XB_OFF);
    ushort* Wt     = (ushort*)(ws + WT_OFF);
    ushort* Wot    = (ushort*)(ws + WOT_OFF);
    float*  QKVf   = (float*)(ws + QKV_OFF);
    ushort* Qb     = (ushort*)(ws + QB_OFF);
    ushort* Kb     = (ushort*)(ws + KB_OFF);
    ushort* Vt     = (ushort*)(ws + VT_OFF);
    ushort* yb     = (ushort*)(ws + YB_OFF);

    // 1. sin table
    k_sintab<<<512, 256, 0, stream>>>(sintab);
    // 2. x -> bf16
    k_cvt<<<(MROWS * EMB / 4) / 256, 256, 0, stream>>>((const float4*)x, (ushort4*)xb);
    // 3. weight transposes -> bf16 [N][K]
    dim3 tb(32, 8);
    k_transpose_cvt<<<dim3(EMB/32, EMB/32), tb, 0, stream>>>(Wq, EMB, Wt, EMB);
    k_transpose_cvt<<<dim3((NG*HD)/32, EMB/32), tb, 0, stream>>>(Wk, NG*HD, Wt + (size_t)EMB * EMB, EMB);
    k_transpose_cvt<<<dim3((NG*HD)/32, EMB/32), tb, 0, stream>>>(Wv, NG*HD, Wt + (size_t)(EMB + NG*HD) * EMB, EMB);
    k_transpose_cvt<<<dim3(EMB/32, EMB/32), tb, 0, stream>>>(Wo, EMB, Wot, EMB);
    // 4. QKV = x @ [Wq|Wk|Wv]   (f32 out [4096][3072])
    k_gemm_bt<<<dim3(NQK/128, MROWS/128), 256, 0, stream>>>(xb, Wt, QKVf, MROWS, NQK, EMB, nullptr);
    // 5. RoPE + convert Q (scale*log2e folded), K ; transpose-convert V
    const float qscale = 0.08838834764831845f * 1.4426950408889634f;
    k_rope_cvt<<<(BATCH*NH*CTX*64)/256, 256, 0, stream>>>(QKVf, NQK, 0, NH, sintab, Qb, qscale);
    k_rope_cvt<<<(BATCH*NG*CTX*64)/256, 256, 0, stream>>>(QKVf, NQK, EMB, NG, sintab, Kb, 1.0f);
    for (int b = 0; b < BATCH; ++b)
        for (int g = 0; g < NG; ++g) {
            const float* srcv = QKVf + (size_t)b * CTX * NQK + EMB + NG*HD + g*HD;
            ushort* dstv = Vt + (size_t)(b*NG + g) * HD * CTX;
            k_transpose_cvt<<<dim3(HD/32, CTX/32), tb, 0, stream>>>(srcv, NQK, dstv, CTX);
        }
    // 6. attention (2048 blocks x 2 waves, split-KV, longest tiles first)
    k_attn3<<<2048, 128, 0, stream>>>(Qb, Kb, Vt, yb);
    // 7. out = y @ Wo + bo
    k_gemm_bt<<<dim3(EMB/128, MROWS/128), 256, 0, stream>>>(yb, Wot, out, MROWS, EMB, EMB, bo);
}

// Round 4
// 314.316 us; speedup vs baseline: 1.4454x; 1.4454x over previous
//
#include <hip/hip_runtime.h>
#include <hip/hip_bf16.h>
#include <cstdint>
#include <cstddef>

// ---------- constants ----------
#define BATCH 2
#define CTX 2048
#define EMB 2048
#define NH 16
#define NG 4
#define HD 128
#define NQK (EMB + 2*NG*HD)   // 3072 combined QKV output cols
#define MROWS (BATCH*CTX)     // 4096

typedef __bf16 bf16x8 __attribute__((ext_vector_type(8)));
typedef float  f32x4  __attribute__((ext_vector_type(4)));
typedef float  f32x16 __attribute__((ext_vector_type(16)));

__device__ __forceinline__ ushort f2bf(float f) {
    uint32_t u = __float_as_uint(f);
    u += 0x7FFFu + ((u >> 16) & 1u);   // round-to-nearest-even
    return (ushort)(u >> 16);
}

__device__ __forceinline__ uint32_t packbf(float a, float b) {
    ushort lo = __builtin_bit_cast(ushort, (__bf16)a);
    ushort hi = __builtin_bit_cast(ushort, (__bf16)b);
    return (uint32_t)lo | ((uint32_t)hi << 16);
}

__device__ __forceinline__ bf16x8 mkfrag(uint32_t a, uint32_t b, uint32_t c, uint32_t d) {
    union { uint32_t u[4]; bf16x8 v; } z;
    z.u[0] = a; z.u[1] = b; z.u[2] = c; z.u[3] = d;
    return z.v;
}

__device__ __forceinline__ void gload_lds16(const void* g, void* l) {
    __builtin_amdgcn_global_load_lds((const __attribute__((address_space(1))) void*)g,
                                     (__attribute__((address_space(3))) void*)l, 16, 0, 0);
}

// ---------- sin table: sintab[pos][j], j in 0..63 ----------
__global__ __launch_bounds__(256) void k_sintab(float* __restrict__ sintab) {
    int t = blockIdx.x * 256 + threadIdx.x;   // 2048*64
    int j = t & 63, p = t >> 6;
    float theta = 1.0f / powf(10000.0f, (float)(2 * j) / 64.0f);
    sintab[t] = sinf((float)p * theta);
}

// ---------- f32 -> bf16 elementwise (4 per thread) ----------
__global__ __launch_bounds__(256) void k_cvt(const float4* __restrict__ src, ushort4* __restrict__ dst) {
    int i = blockIdx.x * 256 + threadIdx.x;
    float4 v = src[i];
    ushort4 o;
    o.x = f2bf(v.x); o.y = f2bf(v.y); o.z = f2bf(v.z); o.w = f2bf(v.w);
    dst[i] = o;
}

// ---------- tiled transpose f32[R][C] -> bf16 dst[C][R] ----------
__global__ __launch_bounds__(256) void k_transpose_cvt(const float* __restrict__ src, int src_ld,
                                                       ushort* __restrict__ dst, int dst_ld) {
    __shared__ float tile[32][33];
    int tx = threadIdx.x, ty = threadIdx.y;          // 32 x 8
    int c0 = blockIdx.x * 32, r0 = blockIdx.y * 32;
    #pragma unroll
    for (int i = 0; i < 4; ++i)
        tile[ty + i*8][tx] = src[(size_t)(r0 + ty + i*8) * src_ld + c0 + tx];
    __syncthreads();
    #pragma unroll
    for (int i = 0; i < 4; ++i)
        dst[(size_t)(c0 + ty + i*8) * dst_ld + r0 + tx] = f2bf(tile[tx][ty + i*8]);
}

// ---------- RoPE + convert (+ optional scale folded in) ----------
__global__ __launch_bounds__(256) void k_rope_cvt(const float* __restrict__ qkv, int ld, int co, int nh,
                                                  const float* __restrict__ sintab, ushort* __restrict__ out,
                                                  float qs) {
    int t = blockIdx.x * 256 + threadIdx.x;   // BATCH*nh*CTX*64
    int j = t & 63;
    int rest = t >> 6;
    int pos = rest & (CTX - 1);
    int rest2 = rest >> 11;
    int hh = rest2 % nh;
    int b = rest2 / nh;
    const float* base = qkv + (size_t)(b * CTX + pos) * ld + co + hh * HD;
    float a = base[j];
    float bb = base[j + 64];
    float sv = sintab[pos * 64 + j] * qs;
    ushort* ob = out + ((size_t)((b * nh + hh) * CTX + pos)) * HD;
    ob[j]      = f2bf((a - bb) * sv);
    ob[j + 64] = f2bf((bb + a) * sv);
}

// ---------- GEMM: C[M][N] (f32) = A[M][K] (bf16) x Bt[N][K] (bf16), optional bias ----------
__global__ __launch_bounds__(256) void k_gemm_bt(const ushort* __restrict__ A, const ushort* __restrict__ Bt,
                                                 float* __restrict__ C, int M, int N, int K,
                                                 const float* __restrict__ bias) {
    __shared__ __align__(16) ushort As[128 * 32];
    __shared__ __align__(16) ushort Bs[128 * 32];
    int tid = threadIdx.x;
    int lane = tid & 63;
    int wave = tid >> 6;
    int wr = wave >> 1, wc = wave & 1;
    int m0 = blockIdx.y * 128, n0 = blockIdx.x * 128;
    int lr = lane & 15, lg = lane >> 4;

    f32x4 acc[4][4] = {};

    int arow = lane >> 2;        // 0..15 within chunk
    int kpart = (lane & 3) * 8;  // 0,8,16,24

    for (int k0 = 0; k0 < K; k0 += 32) {
        #pragma unroll
        for (int s = 0; s < 2; ++s) {
            int c = wave * 2 + s;
            const ushort* ga = A + (size_t)(m0 + c*16 + arow) * K + k0 + kpart;
            gload_lds16(ga, &As[c * 512]);
            const ushort* gb = Bt + (size_t)(n0 + c*16 + arow) * K + k0 + kpart;
            gload_lds16(gb, &Bs[c * 512]);
        }
        __syncthreads();
        bf16x8 af[4], bfr[4];
        #pragma unroll
        for (int mt = 0; mt < 4; ++mt)
            af[mt] = *(const bf16x8*)&As[(wr*64 + mt*16 + lr) * 32 + lg * 8];
        #pragma unroll
        for (int nt = 0; nt < 4; ++nt)
            bfr[nt] = *(const bf16x8*)&Bs[(wc*64 + nt*16 + lr) * 32 + lg * 8];
        #pragma unroll
        for (int mt = 0; mt < 4; ++mt)
            #pragma unroll
            for (int nt = 0; nt < 4; ++nt)
                acc[mt][nt] = __builtin_amdgcn_mfma_f32_16x16x32_bf16(af[mt], bfr[nt], acc[mt][nt], 0, 0, 0);
        __syncthreads();
    }

    #pragma unroll
    for (int mt = 0; mt < 4; ++mt) {
        #pragma unroll
        for (int nt = 0; nt < 4; ++nt) {
            int col = n0 + wc*64 + nt*16 + lr;
            float bv = bias ? bias[col] : 0.0f;
            #pragma unroll
            for (int r = 0; r < 4; ++r) {
                int row = m0 + wr*64 + mt*16 + lg*4 + r;
                C[(size_t)row * N + col] = acc[mt][nt][r] + bv;
            }
        }
    }
}

// ---------- flash attention v3: 2-wave split-KV blocks, 32 q-rows / block ----------
// Qb [B][NH][CTX][HD] (pre-scaled by 1/sqrt(128)*log2(e)), Kb [B][NG][CTX][HD], Vt [B][NG][HD][CTX]
// y [B*CTX][NH*HD] bf16
// Block B: q-tile t = 63-(B>>5), head bh = B&31. Wave w in {0,1} takes kv-steps w, w+2, ...
// Private (m,l,O) per wave; merged via LDS at the end.
// NOTE: no min-waves clause — round-3's (128,4) capped VGPR at 64 and spilled
// the accumulators to scratch (313MB fetch + 356MB write per dispatch).
__global__ __launch_bounds__(128) void k_attn3(const ushort* __restrict__ Qb, const ushort* __restrict__ Kb,
                                               const ushort* __restrict__ Vt, ushort* __restrict__ y) {
    __shared__ __align__(16) float sOd[32][128];
    __shared__ float sm[32], sl[32];
    int lane = threadIdx.x & 63;
    int w    = threadIdx.x >> 6;   // 0 or 1
    int B  = blockIdx.x;
    int t  = 63 - (B >> 5);        // q-tile index, 0..63 (longest first)
    int bh = B & 31;
    int b = bh >> 4, h = bh & 15, g = h >> 2;
    int ln = lane & 31, hi = lane >> 5;
    int q0 = t * 32;

    // Q fragments: B-operand, col = ln = q row, k(hd) = s*16 + hi*8 + e
    const ushort* qrow = Qb + ((size_t)((b*NH + h) * CTX) + q0 + ln) * HD + hi * 8;
    bf16x8 qf[8];
    #pragma unroll
    for (int s = 0; s < 8; ++s) qf[s] = *(const bf16x8*)(qrow + s * 16);

    const ushort* kbase = Kb + (size_t)(b*NG + g) * CTX * HD;
    const ushort* vbase = Vt + (size_t)(b*NG + g) * HD * CTX;

    f32x16 od[4] = {};             // O: row q = (r&3)+8*(r>>2)+4*hi, col d = dt*32+ln
    float m = -1e30f, lsum = 0.0f; // per q = ln (lanes l and l^32 hold same q)

    int nsteps = t + 1;
    for (int si = w; si < nsteps; si += 2) {
        int kv0 = si * 32;
        // S^T = K_tile . Q_tile^T  (rows = kv, cols = q); two acc chains for ILP
        f32x16 st0 = {}, st1 = {};
        const ushort* kp = kbase + ((size_t)(kv0 + ln)) * HD + hi * 8;
        #pragma unroll
        for (int s = 0; s < 4; ++s) {
            bf16x8 kfa = *(const bf16x8*)(kp + (2*s) * 16);
            bf16x8 kfb = *(const bf16x8*)(kp + (2*s+1) * 16);
            st0 = __builtin_amdgcn_mfma_f32_32x32x16_bf16(kfa, qf[2*s],   st0, 0, 0, 0);
            st1 = __builtin_amdgcn_mfma_f32_32x32x16_bf16(kfb, qf[2*s+1], st1, 0, 0, 0);
        }
        f32x16 st = st0 + st1;
        // V fragments for this kv tile (issue loads early)
        bf16x8 vf[8];
        #pragma unroll
        for (int dt = 0; dt < 4; ++dt)
            #pragma unroll
            for (int ks = 0; ks < 2; ++ks)
                vf[dt*2 + ks] = *(const bf16x8*)(vbase + (size_t)(dt*32 + ln) * CTX + kv0 + ks*16 + hi*8);

        // causal mask — only the diagonal tile
        if (kv0 == q0) {
            #pragma unroll
            for (int r = 0; r < 16; ++r) {
                int kl = (r & 3) + 8*(r >> 2) + 4*hi;
                if (kl > ln) st[r] = -1e30f;
            }
        }
        // tile max: tree reduce in-register + one cross-half exchange
        float m8[8];
        #pragma unroll
        for (int r = 0; r < 8; ++r) m8[r] = fmaxf(st[r], st[r+8]);
        #pragma unroll
        for (int r = 0; r < 4; ++r) m8[r] = fmaxf(m8[r], m8[r+4]);
        float pmax = fmaxf(fmaxf(m8[0], m8[1]), fmaxf(m8[2], m8[3]));
        pmax = fmaxf(pmax, __shfl_xor(pmax, 32, 64));

        // defer-max: rescale O only when the running max grows by > 8 (log2 domain)
        if (!__all(pmax <= m + 8.0f)) {
            float mnew = fmaxf(m, pmax);
            float alpha = exp2f(m - mnew);
            lsum *= alpha;
            m = mnew;
            #pragma unroll
            for (int r = 0; r < 16; ++r) {
                float ar = __shfl(alpha, (r & 3) + 8*(r >> 2) + 4*hi, 64);
                #pragma unroll
                for (int dt = 0; dt < 4; ++dt) od[dt][r] *= ar;
            }
        }
        // P = exp2(S - m), row sum
        float p[16];
        float ls = 0.0f;
        #pragma unroll
        for (int r = 0; r < 16; ++r) { p[r] = exp2f(st[r] - m); ls += p[r]; }
        lsum += ls + __shfl_xor(ls, 32, 64);

        // pack P to bf16 pairs and redistribute into PV A-fragment layout
        uint32_t wp[8], xp[8];
        #pragma unroll
        for (int j = 0; j < 8; ++j) wp[j] = packbf(p[2*j], p[2*j + 1]);
        #pragma unroll
        for (int j = 0; j < 8; ++j) xp[j] = (uint32_t)__shfl_xor((int)wp[j], 32, 64);
        bf16x8 pa0 = hi ? mkfrag(xp[2], xp[3], wp[2], wp[3]) : mkfrag(wp[0], wp[1], xp[0], xp[1]);
        bf16x8 pa1 = hi ? mkfrag(xp[6], xp[7], wp[6], wp[7]) : mkfrag(wp[4], wp[5], xp[4], xp[5]);

        // O += P . V  (4 independent d-tile chains)
        #pragma unroll
        for (int dt = 0; dt < 4; ++dt) {
            od[dt] = __builtin_amdgcn_mfma_f32_32x32x16_bf16(pa0, vf[dt*2 + 0], od[dt], 0, 0, 0);
            od[dt] = __builtin_amdgcn_mfma_f32_32x32x16_bf16(pa1, vf[dt*2 + 1], od[dt], 0, 0, 0);
        }
    }

    // ---- merge the two waves' partials ----
    if (w == 1) {
        #pragma unroll
        for (int r = 0; r < 16; ++r) {
            int ri = (r & 3) + 8*(r >> 2) + 4*hi;
            #pragma unroll
            for (int dt = 0; dt < 4; ++dt) sOd[ri][dt*32 + ln] = od[dt][r];
        }
        if (hi == 0) { sm[ln] = m; sl[ln] = lsum; }
    }
    __syncthreads();
    if (w == 0) {
        float m1 = sm[ln], l1 = sl[ln];
        float mnew = fmaxf(m, m1);
        float a0 = exp2f(m - mnew);
        float a1 = exp2f(m1 - mnew);
        float inv = 1.0f / (lsum * a0 + l1 * a1);
        #pragma unroll
        for (int r = 0; r < 16; ++r) {
            int ri = (r & 3) + 8*(r >> 2) + 4*hi;
            float a0r = __shfl(a0, ri, 64);
            float a1r = __shfl(a1, ri, 64);
            float ivr = __shfl(inv, ri, 64);
            int row = q0 + ri;
            #pragma unroll
            for (int dt = 0; dt < 4; ++dt) {
                float v = (od[dt][r] * a0r + sOd[ri][dt*32 + ln] * a1r) * ivr;
                y[((size_t)(b*CTX + row)) * (NH*HD) + h*HD + dt*32 + ln] = f2bf(v);
            }
        }
    }
}

// ---------- workspace layout (bytes) ----------
#define SIN_OFF   ((size_t)0)
#define XB_OFF    ((size_t)524288)
#define WT_OFF    ((size_t)17301504)
#define WOT_OFF   ((size_t)29884416)
#define QKV_OFF   ((size_t)38273024)
#define QB_OFF    ((size_t)88604672)
#define KB_OFF    ((size_t)105381888)
#define VT_OFF    ((size_t)109576192)
#define YB_OFF    ((size_t)113770496)

extern "C" void kernel_launch(void* const* d_in, const int* in_sizes, int n_in,
                              void* d_out, int out_size, void* d_ws, size_t ws_size,
                              hipStream_t stream) {
    const float* x  = (const float*)d_in[0];
    const float* Wq = (const float*)d_in[1];
    const float* Wk = (const float*)d_in[2];
    const float* Wv = (const float*)d_in[3];
    const float* Wo = (const float*)d_in[4];
    const float* bo = (const float*)d_in[5];
    float* out = (float*)d_out;
    char* ws = (char*)d_ws;

    float*  sintab = (float*)(ws + SIN_OFF);
    ushort* xb     = (ushort*)(ws + XB_OFF);
    ushort* Wt     = (ushort*)(ws + WT_OFF);
    ushort* Wot    = (ushort*)(ws + WOT_OFF);
    float*  QKVf   = (float*)(ws + QKV_OFF);
    ushort* Qb     = (ushort*)(ws + QB_OFF);
    ushort* Kb     = (ushort*)(ws + KB_OFF);
    ushort* Vt     = (ushort*)(ws + VT_OFF);
    ushort* yb     = (ushort*)(ws + YB_OFF);

    // 1. sin table
    k_sintab<<<512, 256, 0, stream>>>(sintab);
    // 2. x -> bf16
    k_cvt<<<(MROWS * EMB / 4) / 256, 256, 0, stream>>>((const float4*)x, (ushort4*)xb);
    // 3. weight transposes -> bf16 [N][K]
    dim3 tb(32, 8);
    k_transpose_cvt<<<dim3(EMB/32, EMB/32), tb, 0, stream>>>(Wq, EMB, Wt, EMB);
    k_transpose_cvt<<<dim3((NG*HD)/32, EMB/32), tb, 0, stream>>>(Wk, NG*HD, Wt + (size_t)EMB * EMB, EMB);
    k_transpose_cvt<<<dim3((NG*HD)/32, EMB/32), tb, 0, stream>>>(Wv, NG*HD, Wt + (size_t)(EMB + NG*HD) * EMB, EMB);
    k_transpose_cvt<<<dim3(EMB/32, EMB/32), tb, 0, stream>>>(Wo, EMB, Wot, EMB);
    // 4. QKV = x @ [Wq|Wk|Wv]   (f32 out [4096][3072])
    k_gemm_bt<<<dim3(NQK/128, MROWS/128), 256, 0, stream>>>(xb, Wt, QKVf, MROWS, NQK, EMB, nullptr);
    // 5. RoPE + convert Q (scale*log2e folded), K ; transpose-convert V
    const float qscale = 0.08838834764831845f * 1.4426950408889634f;
    k_rope_cvt<<<(BATCH*NH*CTX*64)/256, 256, 0, stream>>>(QKVf, NQK, 0, NH, sintab, Qb, qscale);
    k_rope_cvt<<<(BATCH*NG*CTX*64)/256, 256, 0, stream>>>(QKVf, NQK, EMB, NG, sintab, Kb, 1.0f);
    for (int b = 0; b < BATCH; ++b)
        for (int g = 0; g < NG; ++g) {
            const float* srcv = QKVf + (size_t)b * CTX * NQK + EMB + NG*HD + g*HD;
            ushort* dstv = Vt + (size_t)(b*NG + g) * HD * CTX;
            k_transpose_cvt<<<dim3(HD/32, CTX/32), tb, 0, stream>>>(srcv, NQK, dstv, CTX);
        }
    // 6. attention (2048 blocks x 2 waves, split-KV, longest tiles first)
    k_attn3<<<2048, 128, 0, stream>>>(Qb, Kb, Vt, yb);
    // 7. out = y @ Wo + bo
    k_gemm_bt<<<dim3(EMB/128, MROWS/128), 256, 0, stream>>>(yb, Wot, out, MROWS, EMB, EMB, bo);
}

// Round 5
// 295.306 us; speedup vs baseline: 1.5385x; 1.0644x over previous
//
#include <hip/hip_runtime.h>
#include <hip/hip_bf16.h>
#include <cstdint>
#include <cstddef>

// ---------- constants ----------
#define BATCH 2
#define CTX 2048
#define EMB 2048
#define NH 16
#define NG 4
#define HD 128
#define NQK (EMB + 2*NG*HD)   // 3072 combined QKV output cols
#define MROWS (BATCH*CTX)     // 4096

typedef __bf16 bf16x8 __attribute__((ext_vector_type(8)));
typedef float  f32x4  __attribute__((ext_vector_type(4)));
typedef float  f32x16 __attribute__((ext_vector_type(16)));

__device__ __forceinline__ ushort f2bf(float f) {
    uint32_t u = __float_as_uint(f);
    u += 0x7FFFu + ((u >> 16) & 1u);   // round-to-nearest-even
    return (ushort)(u >> 16);
}

__device__ __forceinline__ uint32_t packbf(float a, float b) {
    ushort lo = __builtin_bit_cast(ushort, (__bf16)a);
    ushort hi = __builtin_bit_cast(ushort, (__bf16)b);
    return (uint32_t)lo | ((uint32_t)hi << 16);
}

__device__ __forceinline__ bf16x8 mkfrag(uint32_t a, uint32_t b, uint32_t c, uint32_t d) {
    union { uint32_t u[4]; bf16x8 v; } z;
    z.u[0] = a; z.u[1] = b; z.u[2] = c; z.u[3] = d;
    return z.v;
}

__device__ __forceinline__ void gload_lds16(const void* g, void* l) {
    __builtin_amdgcn_global_load_lds((const __attribute__((address_space(1))) void*)g,
                                     (__attribute__((address_space(3))) void*)l, 16, 0, 0);
}

// ---------- sin table: sintab[pos][j], j in 0..63 ----------
__global__ __launch_bounds__(256) void k_sintab(float* __restrict__ sintab) {
    int t = blockIdx.x * 256 + threadIdx.x;   // 2048*64
    int j = t & 63, p = t >> 6;
    float theta = 1.0f / powf(10000.0f, (float)(2 * j) / 64.0f);
    sintab[t] = sinf((float)p * theta);
}

// ---------- f32 -> bf16 elementwise (4 per thread) ----------
__global__ __launch_bounds__(256) void k_cvt(const float4* __restrict__ src, ushort4* __restrict__ dst) {
    int i = blockIdx.x * 256 + threadIdx.x;
    float4 v = src[i];
    ushort4 o;
    o.x = f2bf(v.x); o.y = f2bf(v.y); o.z = f2bf(v.z); o.w = f2bf(v.w);
    dst[i] = o;
}

// ---------- tiled transpose f32[R][C] -> bf16 dst[C][R] ----------
__global__ __launch_bounds__(256) void k_transpose_cvt(const float* __restrict__ src, int src_ld,
                                                       ushort* __restrict__ dst, int dst_ld) {
    __shared__ float tile[32][33];
    int tx = threadIdx.x, ty = threadIdx.y;          // 32 x 8
    int c0 = blockIdx.x * 32, r0 = blockIdx.y * 32;
    #pragma unroll
    for (int i = 0; i < 4; ++i)
        tile[ty + i*8][tx] = src[(size_t)(r0 + ty + i*8) * src_ld + c0 + tx];
    __syncthreads();
    #pragma unroll
    for (int i = 0; i < 4; ++i)
        dst[(size_t)(c0 + ty + i*8) * dst_ld + r0 + tx] = f2bf(tile[tx][ty + i*8]);
}

// ---------- V transpose: all (b,g) tiles in one launch ----------
// src f32 QKVf[b*CTX + row][NQK] cols [EMB+NG*HD + g*HD ...], dst bf16 Vt[(b*NG+g)][HD][CTX]
__global__ __launch_bounds__(256) void k_vtrans(const float* __restrict__ qkvf, ushort* __restrict__ Vt) {
    __shared__ float tile[32][33];
    int z = blockIdx.z;                               // 0..7 = b*NG+g
    int b = z >> 2, g = z & 3;
    const float* src = qkvf + (size_t)b * CTX * NQK + EMB + NG*HD + g*HD;
    ushort* dst = Vt + (size_t)z * HD * CTX;
    int tx = threadIdx.x, ty = threadIdx.y;          // 32 x 8
    int c0 = blockIdx.x * 32, r0 = blockIdx.y * 32;  // c over HD, r over CTX
    #pragma unroll
    for (int i = 0; i < 4; ++i)
        tile[ty + i*8][tx] = src[(size_t)(r0 + ty + i*8) * NQK + c0 + tx];
    __syncthreads();
    #pragma unroll
    for (int i = 0; i < 4; ++i)
        dst[(size_t)(c0 + ty + i*8) * CTX + r0 + tx] = f2bf(tile[tx][ty + i*8]);
}

// ---------- RoPE + convert (+ optional scale folded in) ----------
__global__ __launch_bounds__(256) void k_rope_cvt(const float* __restrict__ qkv, int ld, int co, int nh,
                                                  const float* __restrict__ sintab, ushort* __restrict__ out,
                                                  float qs) {
    int t = blockIdx.x * 256 + threadIdx.x;   // BATCH*nh*CTX*64
    int j = t & 63;
    int rest = t >> 6;
    int pos = rest & (CTX - 1);
    int rest2 = rest >> 11;
    int hh = rest2 % nh;
    int b = rest2 / nh;
    const float* base = qkv + (size_t)(b * CTX + pos) * ld + co + hh * HD;
    float a = base[j];
    float bb = base[j + 64];
    float sv = sintab[pos * 64 + j] * qs;
    ushort* ob = out + ((size_t)((b * nh + hh) * CTX + pos)) * HD;
    ob[j]      = f2bf((a - bb) * sv);
    ob[j + 64] = f2bf((bb + a) * sv);
}

// ---------- GEMM: C[M][N] (f32) = A[M][K] (bf16) x Bt[N][K] (bf16), optional bias ----------
__global__ __launch_bounds__(256) void k_gemm_bt(const ushort* __restrict__ A, const ushort* __restrict__ Bt,
                                                 float* __restrict__ C, int M, int N, int K,
                                                 const float* __restrict__ bias) {
    __shared__ __align__(16) ushort As[128 * 32];
    __shared__ __align__(16) ushort Bs[128 * 32];
    int tid = threadIdx.x;
    int lane = tid & 63;
    int wave = tid >> 6;
    int wr = wave >> 1, wc = wave & 1;
    int m0 = blockIdx.y * 128, n0 = blockIdx.x * 128;
    int lr = lane & 15, lg = lane >> 4;

    f32x4 acc[4][4] = {};

    int arow = lane >> 2;        // 0..15 within chunk
    int kpart = (lane & 3) * 8;  // 0,8,16,24

    for (int k0 = 0; k0 < K; k0 += 32) {
        #pragma unroll
        for (int s = 0; s < 2; ++s) {
            int c = wave * 2 + s;
            const ushort* ga = A + (size_t)(m0 + c*16 + arow) * K + k0 + kpart;
            gload_lds16(ga, &As[c * 512]);
            const ushort* gb = Bt + (size_t)(n0 + c*16 + arow) * K + k0 + kpart;
            gload_lds16(gb, &Bs[c * 512]);
        }
        __syncthreads();
        bf16x8 af[4], bfr[4];
        #pragma unroll
        for (int mt = 0; mt < 4; ++mt)
            af[mt] = *(const bf16x8*)&As[(wr*64 + mt*16 + lr) * 32 + lg * 8];
        #pragma unroll
        for (int nt = 0; nt < 4; ++nt)
            bfr[nt] = *(const bf16x8*)&Bs[(wc*64 + nt*16 + lr) * 32 + lg * 8];
        #pragma unroll
        for (int mt = 0; mt < 4; ++mt)
            #pragma unroll
            for (int nt = 0; nt < 4; ++nt)
                acc[mt][nt] = __builtin_amdgcn_mfma_f32_16x16x32_bf16(af[mt], bfr[nt], acc[mt][nt], 0, 0, 0);
        __syncthreads();
    }

    #pragma unroll
    for (int mt = 0; mt < 4; ++mt) {
        #pragma unroll
        for (int nt = 0; nt < 4; ++nt) {
            int col = n0 + wc*64 + nt*16 + lr;
            float bv = bias ? bias[col] : 0.0f;
            #pragma unroll
            for (int r = 0; r < 4; ++r) {
                int row = m0 + wr*64 + mt*16 + lg*4 + r;
                C[(size_t)row * N + col] = acc[mt][nt][r] + bv;
            }
        }
    }
}

// ---------- flash attention v4: 2-wave split-KV blocks, Q in swizzled LDS, 32 q-rows / block ----------
// Register diet vs v3: Q tile in LDS (shared by both waves, -32 VGPR), single QK acc chain (-16),
// V fragments streamed per ks-half (-24 peak). Target VGPR <= 128 -> 4 waves/SIMD.
// LDS: Qs (8KB, swizzled) overlaid by merge buffer sOd (16KB, used strictly after Q is dead).
__global__ __launch_bounds__(128) void k_attn4(const ushort* __restrict__ Qb, const ushort* __restrict__ Kb,
                                               const ushort* __restrict__ Vt, ushort* __restrict__ y) {
    __shared__ __align__(16) char smem[16640];
    char*  Qs  = smem;                         // bf16 [32][128], chunk-swizzled
    float* sOd = (float*)smem;                 // f32 [32][128] (overlay, post-loop only)
    float* sm  = (float*)(smem + 16384);
    float* sl  = (float*)(smem + 16512);

    int lane = threadIdx.x & 63;
    int w    = threadIdx.x >> 6;   // 0 or 1
    int B  = blockIdx.x;
    int t  = 63 - (B >> 5);        // q-tile index, 0..63 (longest first)
    int bh = B & 31;
    int b = bh >> 4, h = bh & 15, g = h >> 2;
    int ln = lane & 31, hi = lane >> 5;
    int q0 = t * 32;

    // cooperative Q load: 32 rows x 128 d (256B/row), XOR-swizzled 16B chunks
    {
        int r  = threadIdx.x >> 2;
        int c0 = threadIdx.x & 3;
        const ushort* qg = Qb + ((size_t)((b*NH + h) * CTX) + q0 + r) * HD;
        #pragma unroll
        for (int it = 0; it < 4; ++it) {
            int c = c0 + it * 4;                    // chunk 0..15
            bf16x8 v = *(const bf16x8*)(qg + c * 8);
            *(bf16x8*)(Qs + r * 256 + ((c ^ (r & 7)) * 16)) = v;
        }
    }
    __syncthreads();

    const ushort* kbase = Kb + (size_t)(b*NG + g) * CTX * HD;
    const ushort* vbase = Vt + (size_t)(b*NG + g) * HD * CTX;

    f32x16 od[4] = {};             // O: row q = (r&3)+8*(r>>2)+4*hi, col d = dt*32+ln
    float m = -1e30f, lsum = 0.0f; // per q = ln (lanes l and l^32 hold same q)

    int nsteps = t + 1;
    for (int si = w; si < nsteps; si += 2) {
        int kv0 = si * 32;
        // S^T = K_tile . Q_tile^T  (rows = kv, cols = q); Q B-fragments from swizzled LDS
        f32x16 st = {};
        const ushort* kp = kbase + ((size_t)(kv0 + ln)) * HD + hi * 8;
        #pragma unroll
        for (int s = 0; s < 8; ++s) {
            bf16x8 kf = *(const bf16x8*)(kp + s * 16);
            bf16x8 qf = *(const bf16x8*)(Qs + ln * 256 + (((2*s + hi) ^ (ln & 7)) * 16));
            st = __builtin_amdgcn_mfma_f32_32x32x16_bf16(kf, qf, st, 0, 0, 0);
        }

        // causal mask — only the diagonal tile
        if (kv0 == q0) {
            #pragma unroll
            for (int r = 0; r < 16; ++r) {
                int kl = (r & 3) + 8*(r >> 2) + 4*hi;
                if (kl > ln) st[r] = -1e30f;
            }
        }
        // tile max: tree reduce in-register + one cross-half exchange
        float m8[8];
        #pragma unroll
        for (int r = 0; r < 8; ++r) m8[r] = fmaxf(st[r], st[r+8]);
        #pragma unroll
        for (int r = 0; r < 4; ++r) m8[r] = fmaxf(m8[r], m8[r+4]);
        float pmax = fmaxf(fmaxf(m8[0], m8[1]), fmaxf(m8[2], m8[3]));
        pmax = fmaxf(pmax, __shfl_xor(pmax, 32, 64));

        // defer-max: rescale O only when the running max grows by > 8 (log2 domain)
        if (!__all(pmax <= m + 8.0f)) {
            float mnew = fmaxf(m, pmax);
            float alpha = exp2f(m - mnew);
            lsum *= alpha;
            m = mnew;
            #pragma unroll
            for (int r = 0; r < 16; ++r) {
                float ar = __shfl(alpha, (r & 3) + 8*(r >> 2) + 4*hi, 64);
                #pragma unroll
                for (int dt = 0; dt < 4; ++dt) od[dt][r] *= ar;
            }
        }
        // P = exp2(S - m) in place, row sum
        float ls = 0.0f;
        #pragma unroll
        for (int r = 0; r < 16; ++r) { st[r] = exp2f(st[r] - m); ls += st[r]; }
        lsum += ls + __shfl_xor(ls, 32, 64);

        // O += P.V, one ks-half at a time (keys 0..15 then 16..31); V streamed
        #pragma unroll
        for (int ks = 0; ks < 2; ++ks) {
            uint32_t w0 = packbf(st[8*ks+0], st[8*ks+1]);
            uint32_t w1 = packbf(st[8*ks+2], st[8*ks+3]);
            uint32_t w2 = packbf(st[8*ks+4], st[8*ks+5]);
            uint32_t w3 = packbf(st[8*ks+6], st[8*ks+7]);
            uint32_t x0 = (uint32_t)__shfl_xor((int)w0, 32, 64);
            uint32_t x1 = (uint32_t)__shfl_xor((int)w1, 32, 64);
            uint32_t x2 = (uint32_t)__shfl_xor((int)w2, 32, 64);
            uint32_t x3 = (uint32_t)__shfl_xor((int)w3, 32, 64);
            bf16x8 pa = hi ? mkfrag(x2, x3, w2, w3) : mkfrag(w0, w1, x0, x1);
            const ushort* vp = vbase + kv0 + ks*16 + hi*8;
            #pragma unroll
            for (int dt = 0; dt < 4; ++dt) {
                bf16x8 vf = *(const bf16x8*)(vp + (size_t)(dt*32 + ln) * CTX);
                od[dt] = __builtin_amdgcn_mfma_f32_32x32x16_bf16(pa, vf, od[dt], 0, 0, 0);
            }
        }
    }

    // ---- merge the two waves' partials (sOd overlays Qs: barrier first) ----
    __syncthreads();
    if (w == 1) {
        #pragma unroll
        for (int r = 0; r < 16; ++r) {
            int ri = (r & 3) + 8*(r >> 2) + 4*hi;
            #pragma unroll
            for (int dt = 0; dt < 4; ++dt) sOd[ri*128 + dt*32 + ln] = od[dt][r];
        }
        if (hi == 0) { sm[ln] = m; sl[ln] = lsum; }
    }
    __syncthreads();
    if (w == 0) {
        float m1 = sm[ln], l1 = sl[ln];
        float mnew = fmaxf(m, m1);
        float a0 = exp2f(m - mnew);
        float a1 = exp2f(m1 - mnew);
        float inv = 1.0f / (lsum * a0 + l1 * a1);
        #pragma unroll
        for (int r = 0; r < 16; ++r) {
            int ri = (r & 3) + 8*(r >> 2) + 4*hi;
            float a0r = __shfl(a0, ri, 64);
            float a1r = __shfl(a1, ri, 64);
            float ivr = __shfl(inv, ri, 64);
            int row = q0 + ri;
            #pragma unroll
            for (int dt = 0; dt < 4; ++dt) {
                float v = (od[dt][r] * a0r + sOd[ri*128 + dt*32 + ln] * a1r) * ivr;
                y[((size_t)(b*CTX + row)) * (NH*HD) + h*HD + dt*32 + ln] = f2bf(v);
            }
        }
    }
}

// ---------- workspace layout (bytes) ----------
#define SIN_OFF   ((size_t)0)
#define XB_OFF    ((size_t)524288)
#define WT_OFF    ((size_t)17301504)
#define WOT_OFF   ((size_t)29884416)
#define QKV_OFF   ((size_t)38273024)
#define QB_OFF    ((size_t)88604672)
#define KB_OFF    ((size_t)105381888)
#define VT_OFF    ((size_t)109576192)
#define YB_OFF    ((size_t)113770496)

extern "C" void kernel_launch(void* const* d_in, const int* in_sizes, int n_in,
                              void* d_out, int out_size, void* d_ws, size_t ws_size,
                              hipStream_t stream) {
    const float* x  = (const float*)d_in[0];
    const float* Wq = (const float*)d_in[1];
    const float* Wk = (const float*)d_in[2];
    const float* Wv = (const float*)d_in[3];
    const float* Wo = (const float*)d_in[4];
    const float* bo = (const float*)d_in[5];
    float* out = (float*)d_out;
    char* ws = (char*)d_ws;

    float*  sintab = (float*)(ws + SIN_OFF);
    ushort* xb     = (ushort*)(ws + XB_OFF);
    ushort* Wt     = (ushort*)(ws + WT_OFF);
    ushort* Wot    = (ushort*)(ws + WOT_OFF);
    float*  QKVf   = (float*)(ws + QKV_OFF);
    ushort* Qb     = (ushort*)(ws + QB_OFF);
    ushort* Kb     = (ushort*)(ws + KB_OFF);
    ushort* Vt     = (ushort*)(ws + VT_OFF);
    ushort* yb     = (ushort*)(ws + YB_OFF);

    // 1. sin table
    k_sintab<<<512, 256, 0, stream>>>(sintab);
    // 2. x -> bf16
    k_cvt<<<(MROWS * EMB / 4) / 256, 256, 0, stream>>>((const float4*)x, (ushort4*)xb);
    // 3. weight transposes -> bf16 [N][K]
    dim3 tb(32, 8);
    k_transpose_cvt<<<dim3(EMB/32, EMB/32), tb, 0, stream>>>(Wq, EMB, Wt, EMB);
    k_transpose_cvt<<<dim3((NG*HD)/32, EMB/32), tb, 0, stream>>>(Wk, NG*HD, Wt + (size_t)EMB * EMB, EMB);
    k_transpose_cvt<<<dim3((NG*HD)/32, EMB/32), tb, 0, stream>>>(Wv, NG*HD, Wt + (size_t)(EMB + NG*HD) * EMB, EMB);
    k_transpose_cvt<<<dim3(EMB/32, EMB/32), tb, 0, stream>>>(Wo, EMB, Wot, EMB);
    // 4. QKV = x @ [Wq|Wk|Wv]   (f32 out [4096][3072])
    k_gemm_bt<<<dim3(NQK/128, MROWS/128), 256, 0, stream>>>(xb, Wt, QKVf, MROWS, NQK, EMB, nullptr);
    // 5. RoPE + convert Q (scale*log2e folded), K ; transpose-convert V (one launch)
    const float qscale = 0.08838834764831845f * 1.4426950408889634f;
    k_rope_cvt<<<(BATCH*NH*CTX*64)/256, 256, 0, stream>>>(QKVf, NQK, 0, NH, sintab, Qb, qscale);
    k_rope_cvt<<<(BATCH*NG*CTX*64)/256, 256, 0, stream>>>(QKVf, NQK, EMB, NG, sintab, Kb, 1.0f);
    k_vtrans<<<dim3(HD/32, CTX/32, BATCH*NG), tb, 0, stream>>>(QKVf, Vt);
    // 6. attention (2048 blocks x 2 waves, split-KV, Q in LDS, longest tiles first)
    k_attn4<<<2048, 128, 0, stream>>>(Qb, Kb, Vt, yb);
    // 7. out = y @ Wo + bo
    k_gemm_bt<<<dim3(EMB/128, MROWS/128), 256, 0, stream>>>(yb, Wot, out, MROWS, EMB, EMB, bo);
}

// Round 6
// 252.005 us; speedup vs baseline: 1.8028x; 1.1718x over previous
//
#include <hip/hip_runtime.h>
#include <hip/hip_bf16.h>
#include <cstdint>
#include <cstddef>

// ---------- constants ----------
#define BATCH 2
#define CTX 2048
#define EMB 2048
#define NH 16
#define NG 4
#define HD 128
#define NQK (EMB + 2*NG*HD)   // 3072 combined QKV output cols
#define MROWS (BATCH*CTX)     // 4096

typedef __bf16 bf16x8 __attribute__((ext_vector_type(8)));
typedef float  f32x4  __attribute__((ext_vector_type(4)));
typedef float  f32x16 __attribute__((ext_vector_type(16)));

__device__ __forceinline__ ushort f2bf(float f) {
    uint32_t u = __float_as_uint(f);
    u += 0x7FFFu + ((u >> 16) & 1u);   // round-to-nearest-even
    return (ushort)(u >> 16);
}

__device__ __forceinline__ uint32_t packbf(float a, float b) {
    ushort lo = __builtin_bit_cast(ushort, (__bf16)a);
    ushort hi = __builtin_bit_cast(ushort, (__bf16)b);
    return (uint32_t)lo | ((uint32_t)hi << 16);
}

__device__ __forceinline__ bf16x8 mkfrag(uint32_t a, uint32_t b, uint32_t c, uint32_t d) {
    union { uint32_t u[4]; bf16x8 v; } z;
    z.u[0] = a; z.u[1] = b; z.u[2] = c; z.u[3] = d;
    return z.v;
}

__device__ __forceinline__ void gload_lds16(const void* g, void* l) {
    __builtin_amdgcn_global_load_lds((const __attribute__((address_space(1))) void*)g,
                                     (__attribute__((address_space(3))) void*)l, 16, 0, 0);
}

// ---------- sin table: sintab[pos][j], j in 0..63 ----------
__global__ __launch_bounds__(256) void k_sintab(float* __restrict__ sintab) {
    int t = blockIdx.x * 256 + threadIdx.x;   // 2048*64
    int j = t & 63, p = t >> 6;
    float theta = 1.0f / powf(10000.0f, (float)(2 * j) / 64.0f);
    sintab[t] = sinf((float)p * theta);
}

// ---------- f32 -> bf16 elementwise (4 per thread) ----------
__global__ __launch_bounds__(256) void k_cvt(const float4* __restrict__ src, ushort4* __restrict__ dst) {
    int i = blockIdx.x * 256 + threadIdx.x;
    float4 v = src[i];
    ushort4 o;
    o.x = f2bf(v.x); o.y = f2bf(v.y); o.z = f2bf(v.z); o.w = f2bf(v.w);
    dst[i] = o;
}

// ---------- tiled transpose f32[R][C] -> bf16 dst[C][R] ----------
__global__ __launch_bounds__(256) void k_transpose_cvt(const float* __restrict__ src, int src_ld,
                                                       ushort* __restrict__ dst, int dst_ld) {
    __shared__ float tile[32][33];
    int tx = threadIdx.x, ty = threadIdx.y;          // 32 x 8
    int c0 = blockIdx.x * 32, r0 = blockIdx.y * 32;
    #pragma unroll
    for (int i = 0; i < 4; ++i)
        tile[ty + i*8][tx] = src[(size_t)(r0 + ty + i*8) * src_ld + c0 + tx];
    __syncthreads();
    #pragma unroll
    for (int i = 0; i < 4; ++i)
        dst[(size_t)(c0 + ty + i*8) * dst_ld + r0 + tx] = f2bf(tile[tx][ty + i*8]);
}

// ---------- RoPE + convert Q: out [B][NH][CTX][HD] bf16 (row-major, staged to LDS later) ----------
__global__ __launch_bounds__(256) void k_rope_q(const float* __restrict__ qkv,
                                                const float* __restrict__ sintab, ushort* __restrict__ out,
                                                float qs) {
    int t = blockIdx.x * 256 + threadIdx.x;   // BATCH*NH*CTX*64
    int j = t & 63;
    int rest = t >> 6;
    int pos = rest & (CTX - 1);
    int rest2 = rest >> 11;
    int hh = rest2 % NH;
    int b = rest2 / NH;
    const float* base = qkv + (size_t)(b * CTX + pos) * NQK + hh * HD;
    float a = base[j];
    float bb = base[j + 64];
    float sv = sintab[pos * 64 + j] * qs;
    ushort* ob = out + ((size_t)((b * NH + hh) * CTX + pos)) * HD;
    ob[j]      = f2bf((a - bb) * sv);
    ob[j + 64] = f2bf((bb + a) * sv);
}

// ---------- RoPE + convert K into MFMA-FRAGMENT-ORDER layout ----------
// Kf[(bg*64+step)*4096 + s*512 + hi*256 + ln*8 + e]  (ushort idx)
//   holds K[step*32+ln][s*16+hi*8+e]  -> attention A-fragment load = base + s*1KB + lane*16B (coalesced)
__global__ __launch_bounds__(256) void k_rope_kf(const float* __restrict__ qkv,
                                                 const float* __restrict__ sintab, ushort* __restrict__ Kf) {
    int t = blockIdx.x * 256 + threadIdx.x;   // BATCH*NG*CTX*64
    int j = t & 63;
    int rest = t >> 6;
    int pos = rest & (CTX - 1);
    int rest2 = rest >> 11;
    int g = rest2 % NG;
    int b = rest2 / NG;
    int bg = b * NG + g;
    const float* base = qkv + (size_t)(b * CTX + pos) * NQK + EMB + g * HD;
    float a = base[j];
    float bb = base[j + 64];
    float sv = sintab[pos * 64 + j];
    // d = j: s=j>>4, hi=(j>>3)&1, e=j&7 ; d = j+64: s += 4
    size_t idx0 = (size_t)(bg * 64 + (pos >> 5)) * 4096
                + (size_t)(j >> 4) * 512 + ((j >> 3) & 1) * 256 + (pos & 31) * 8 + (j & 7);
    Kf[idx0]        = f2bf((a - bb) * sv);
    Kf[idx0 + 2048] = f2bf((bb + a) * sv);   // s+4 -> +4*512
}

// ---------- V -> MFMA-FRAGMENT-ORDER layout ----------
// Vf[((bg*64+step)*8 + dt*2+ks)*512 + lane*8 + e]  holds V[step*32+ks*16+hi*8+e][dt*32+ln]
// (lane = hi*32+ln). Attention B-fragment load = base + (dt*2+ks)*1KB + lane*16B (coalesced).
__global__ __launch_bounds__(256) void k_vfrag(const float* __restrict__ qkvf, ushort* __restrict__ Vf) {
    int lane = threadIdx.x;        // 64
    int dt   = threadIdx.y;        // 4
    int step = blockIdx.x;         // 64
    int bg   = blockIdx.y;         // 8
    int b = bg >> 2, g = bg & 3;
    int ln = lane & 31, hi = lane >> 5;
    int col = EMB + NG*HD + g*HD + dt*32 + ln;
    #pragma unroll
    for (int ks = 0; ks < 2; ++ks) {
        int pos0 = step*32 + ks*16 + hi*8;
        float v[8];
        #pragma unroll
        for (int e = 0; e < 8; ++e)
            v[e] = qkvf[(size_t)(b*CTX + pos0 + e) * NQK + col];
        union { uint32_t u[4]; bf16x8 bv; } z;
        z.u[0] = packbf(v[0], v[1]); z.u[1] = packbf(v[2], v[3]);
        z.u[2] = packbf(v[4], v[5]); z.u[3] = packbf(v[6], v[7]);
        *(bf16x8*)(Vf + ((size_t)(bg*64 + step)*8 + dt*2 + ks) * 512 + lane*8) = z.bv;
    }
}

// ---------- GEMM: C[M][N] (f32) = A[M][K] (bf16) x Bt[N][K] (bf16), optional bias ----------
__global__ __launch_bounds__(256) void k_gemm_bt(const ushort* __restrict__ A, const ushort* __restrict__ Bt,
                                                 float* __restrict__ C, int M, int N, int K,
                                                 const float* __restrict__ bias) {
    __shared__ __align__(16) ushort As[128 * 32];
    __shared__ __align__(16) ushort Bs[128 * 32];
    int tid = threadIdx.x;
    int lane = tid & 63;
    int wave = tid >> 6;
    int wr = wave >> 1, wc = wave & 1;
    int m0 = blockIdx.y * 128, n0 = blockIdx.x * 128;
    int lr = lane & 15, lg = lane >> 4;

    f32x4 acc[4][4] = {};

    int arow = lane >> 2;        // 0..15 within chunk
    int kpart = (lane & 3) * 8;  // 0,8,16,24

    for (int k0 = 0; k0 < K; k0 += 32) {
        #pragma unroll
        for (int s = 0; s < 2; ++s) {
            int c = wave * 2 + s;
            const ushort* ga = A + (size_t)(m0 + c*16 + arow) * K + k0 + kpart;
            gload_lds16(ga, &As[c * 512]);
            const ushort* gb = Bt + (size_t)(n0 + c*16 + arow) * K + k0 + kpart;
            gload_lds16(gb, &Bs[c * 512]);
        }
        __syncthreads();
        bf16x8 af[4], bfr[4];
        #pragma unroll
        for (int mt = 0; mt < 4; ++mt)
            af[mt] = *(const bf16x8*)&As[(wr*64 + mt*16 + lr) * 32 + lg * 8];
        #pragma unroll
        for (int nt = 0; nt < 4; ++nt)
            bfr[nt] = *(const bf16x8*)&Bs[(wc*64 + nt*16 + lr) * 32 + lg * 8];
        #pragma unroll
        for (int mt = 0; mt < 4; ++mt)
            #pragma unroll
            for (int nt = 0; nt < 4; ++nt)
                acc[mt][nt] = __builtin_amdgcn_mfma_f32_16x16x32_bf16(af[mt], bfr[nt], acc[mt][nt], 0, 0, 0);
        __syncthreads();
    }

    #pragma unroll
    for (int mt = 0; mt < 4; ++mt) {
        #pragma unroll
        for (int nt = 0; nt < 4; ++nt) {
            int col = n0 + wc*64 + nt*16 + lr;
            float bv = bias ? bias[col] : 0.0f;
            #pragma unroll
            for (int r = 0; r < 4; ++r) {
                int row = m0 + wr*64 + mt*16 + lg*4 + r;
                C[(size_t)row * N + col] = acc[mt][nt][r] + bv;
            }
        }
    }
}

// ---------- flash attention v5: v4 structure + fragment-order coalesced K/V loads ----------
// Qb [B][NH][CTX][HD] (pre-scaled), Kf/Vf in fragment order (see producers), y [B*CTX][NH*HD] bf16
// 2048 blocks x 2 waves; block B: q-tile t = 63-(B>>5), head bh = B&31; wave w takes steps w, w+2, ...
__global__ __launch_bounds__(128) void k_attn5(const ushort* __restrict__ Qb, const ushort* __restrict__ Kf,
                                               const ushort* __restrict__ Vf, ushort* __restrict__ y) {
    __shared__ __align__(16) char smem[16640];
    char*  Qs  = smem;                         // bf16 [32][128], chunk-swizzled
    float* sOd = (float*)smem;                 // f32 [32][128] (overlay, post-loop only)
    float* sm  = (float*)(smem + 16384);
    float* sl  = (float*)(smem + 16512);

    int lane = threadIdx.x & 63;
    int w    = threadIdx.x >> 6;   // 0 or 1
    int B  = blockIdx.x;
    int t  = 63 - (B >> 5);        // q-tile index, 0..63 (longest first)
    int bh = B & 31;
    int b = bh >> 4, h = bh & 15, g = h >> 2;
    int bg = b * NG + g;
    int ln = lane & 31, hi = lane >> 5;
    int q0 = t * 32;

    // cooperative Q load: 32 rows x 128 d (256B/row), XOR-swizzled 16B chunks
    {
        int r  = threadIdx.x >> 2;
        int c0 = threadIdx.x & 3;
        const ushort* qg = Qb + ((size_t)((b*NH + h) * CTX) + q0 + r) * HD;
        #pragma unroll
        for (int it = 0; it < 4; ++it) {
            int c = c0 + it * 4;                    // chunk 0..15
            bf16x8 v = *(const bf16x8*)(qg + c * 8);
            *(bf16x8*)(Qs + r * 256 + ((c ^ (r & 7)) * 16)) = v;
        }
    }
    __syncthreads();

    // fragment-order bases: +lane*16B, step stride 4096 ushorts (8KB)
    const ushort* kfb = Kf + (size_t)bg * 64 * 4096 + lane * 8;
    const ushort* vfb = Vf + (size_t)bg * 64 * 4096 + lane * 8;

    f32x16 od[4] = {};             // O: row q = (r&3)+8*(r>>2)+4*hi, col d = dt*32+ln
    float m = -1e30f, lsum = 0.0f; // per q = ln (lanes l and l^32 hold same q)

    int nsteps = t + 1;
    for (int si = w; si < nsteps; si += 2) {
        const ushort* kp = kfb + (size_t)si * 4096;
        const ushort* vp = vfb + (size_t)si * 4096;
        // S^T = K_tile . Q_tile^T  (rows = kv, cols = q); Q B-fragments from swizzled LDS
        f32x16 st = {};
        #pragma unroll
        for (int s = 0; s < 8; ++s) {
            bf16x8 kf = *(const bf16x8*)(kp + s * 512);
            bf16x8 qf = *(const bf16x8*)(Qs + ln * 256 + (((2*s + hi) ^ (ln & 7)) * 16));
            st = __builtin_amdgcn_mfma_f32_32x32x16_bf16(kf, qf, st, 0, 0, 0);
        }

        // causal mask — only the diagonal tile
        if (si == t) {
            #pragma unroll
            for (int r = 0; r < 16; ++r) {
                int kl = (r & 3) + 8*(r >> 2) + 4*hi;
                if (kl > ln) st[r] = -1e30f;
            }
        }
        // tile max: tree reduce in-register + one cross-half exchange
        float m8[8];
        #pragma unroll
        for (int r = 0; r < 8; ++r) m8[r] = fmaxf(st[r], st[r+8]);
        #pragma unroll
        for (int r = 0; r < 4; ++r) m8[r] = fmaxf(m8[r], m8[r+4]);
        float pmax = fmaxf(fmaxf(m8[0], m8[1]), fmaxf(m8[2], m8[3]));
        pmax = fmaxf(pmax, __shfl_xor(pmax, 32, 64));

        // defer-max: rescale O only when the running max grows by > 8 (log2 domain)
        if (!__all(pmax <= m + 8.0f)) {
            float mnew = fmaxf(m, pmax);
            float alpha = exp2f(m - mnew);
            lsum *= alpha;
            m = mnew;
            #pragma unroll
            for (int r = 0; r < 16; ++r) {
                float ar = __shfl(alpha, (r & 3) + 8*(r >> 2) + 4*hi, 64);
                #pragma unroll
                for (int dt = 0; dt < 4; ++dt) od[dt][r] *= ar;
            }
        }
        // P = exp2(S - m) in place, row sum
        float ls = 0.0f;
        #pragma unroll
        for (int r = 0; r < 16; ++r) { st[r] = exp2f(st[r] - m); ls += st[r]; }
        lsum += ls + __shfl_xor(ls, 32, 64);

        // O += P.V, one ks-half at a time; V fragments coalesced
        #pragma unroll
        for (int ks = 0; ks < 2; ++ks) {
            uint32_t w0 = packbf(st[8*ks+0], st[8*ks+1]);
            uint32_t w1 = packbf(st[8*ks+2], st[8*ks+3]);
            uint32_t w2 = packbf(st[8*ks+4], st[8*ks+5]);
            uint32_t w3 = packbf(st[8*ks+6], st[8*ks+7]);
            uint32_t x0 = (uint32_t)__shfl_xor((int)w0, 32, 64);
            uint32_t x1 = (uint32_t)__shfl_xor((int)w1, 32, 64);
            uint32_t x2 = (uint32_t)__shfl_xor((int)w2, 32, 64);
            uint32_t x3 = (uint32_t)__shfl_xor((int)w3, 32, 64);
            bf16x8 pa = hi ? mkfrag(x2, x3, w2, w3) : mkfrag(w0, w1, x0, x1);
            #pragma unroll
            for (int dt = 0; dt < 4; ++dt) {
                bf16x8 vf = *(const bf16x8*)(vp + (dt*2 + ks) * 512);
                od[dt] = __builtin_amdgcn_mfma_f32_32x32x16_bf16(pa, vf, od[dt], 0, 0, 0);
            }
        }
    }

    // ---- merge the two waves' partials (sOd overlays Qs: barrier first) ----
    __syncthreads();
    if (w == 1) {
        #pragma unroll
        for (int r = 0; r < 16; ++r) {
            int ri = (r & 3) + 8*(r >> 2) + 4*hi;
            #pragma unroll
            for (int dt = 0; dt < 4; ++dt) sOd[ri*128 + dt*32 + ln] = od[dt][r];
        }
        if (hi == 0) { sm[ln] = m; sl[ln] = lsum; }
    }
    __syncthreads();
    if (w == 0) {
        float m1 = sm[ln], l1 = sl[ln];
        float mnew = fmaxf(m, m1);
        float a0 = exp2f(m - mnew);
        float a1 = exp2f(m1 - mnew);
        float inv = 1.0f / (lsum * a0 + l1 * a1);
        #pragma unroll
        for (int r = 0; r < 16; ++r) {
            int ri = (r & 3) + 8*(r >> 2) + 4*hi;
            float a0r = __shfl(a0, ri, 64);
            float a1r = __shfl(a1, ri, 64);
            float ivr = __shfl(inv, ri, 64);
            int row = q0 + ri;
            #pragma unroll
            for (int dt = 0; dt < 4; ++dt) {
                float v = (od[dt][r] * a0r + sOd[ri*128 + dt*32 + ln] * a1r) * ivr;
                y[((size_t)(b*CTX + row)) * (NH*HD) + h*HD + dt*32 + ln] = f2bf(v);
            }
        }
    }
}

// ---------- workspace layout (bytes) ----------
#define SIN_OFF   ((size_t)0)
#define XB_OFF    ((size_t)524288)
#define WT_OFF    ((size_t)17301504)
#define WOT_OFF   ((size_t)29884416)
#define QKV_OFF   ((size_t)38273024)
#define QB_OFF    ((size_t)88604672)
#define KB_OFF    ((size_t)105381888)
#define VT_OFF    ((size_t)109576192)
#define YB_OFF    ((size_t)113770496)

extern "C" void kernel_launch(void* const* d_in, const int* in_sizes, int n_in,
                              void* d_out, int out_size, void* d_ws, size_t ws_size,
                              hipStream_t stream) {
    const float* x  = (const float*)d_in[0];
    const float* Wq = (const float*)d_in[1];
    const float* Wk = (const float*)d_in[2];
    const float* Wv = (const float*)d_in[3];
    const float* Wo = (const float*)d_in[4];
    const float* bo = (const float*)d_in[5];
    float* out = (float*)d_out;
    char* ws = (char*)d_ws;

    float*  sintab = (float*)(ws + SIN_OFF);
    ushort* xb     = (ushort*)(ws + XB_OFF);
    ushort* Wt     = (ushort*)(ws + WT_OFF);
    ushort* Wot    = (ushort*)(ws + WOT_OFF);
    float*  QKVf   = (float*)(ws + QKV_OFF);
    ushort* Qb     = (ushort*)(ws + QB_OFF);
    ushort* Kf     = (ushort*)(ws + KB_OFF);
    ushort* Vf     = (ushort*)(ws + VT_OFF);
    ushort* yb     = (ushort*)(ws + YB_OFF);

    // 1. sin table
    k_sintab<<<512, 256, 0, stream>>>(sintab);
    // 2. x -> bf16
    k_cvt<<<(MROWS * EMB / 4) / 256, 256, 0, stream>>>((const float4*)x, (ushort4*)xb);
    // 3. weight transposes -> bf16 [N][K]
    dim3 tb(32, 8);
    k_transpose_cvt<<<dim3(EMB/32, EMB/32), tb, 0, stream>>>(Wq, EMB, Wt, EMB);
    k_transpose_cvt<<<dim3((NG*HD)/32, EMB/32), tb, 0, stream>>>(Wk, NG*HD, Wt + (size_t)EMB * EMB, EMB);
    k_transpose_cvt<<<dim3((NG*HD)/32, EMB/32), tb, 0, stream>>>(Wv, NG*HD, Wt + (size_t)(EMB + NG*HD) * EMB, EMB);
    k_transpose_cvt<<<dim3(EMB/32, EMB/32), tb, 0, stream>>>(Wo, EMB, Wot, EMB);
    // 4. QKV = x @ [Wq|Wk|Wv]   (f32 out [4096][3072])
    k_gemm_bt<<<dim3(NQK/128, MROWS/128), 256, 0, stream>>>(xb, Wt, QKVf, MROWS, NQK, EMB, nullptr);
    // 5. RoPE Q (scale*log2e folded); RoPE K -> fragment order; V -> fragment order
    const float qscale = 0.08838834764831845f * 1.4426950408889634f;
    k_rope_q <<<(BATCH*NH*CTX*64)/256, 256, 0, stream>>>(QKVf, sintab, Qb, qscale);
    k_rope_kf<<<(BATCH*NG*CTX*64)/256, 256, 0, stream>>>(QKVf, sintab, Kf);
    k_vfrag<<<dim3(64, BATCH*NG), dim3(64, 4), 0, stream>>>(QKVf, Vf);
    // 6. attention (2048 blocks x 2 waves, split-KV, coalesced fragment loads)
    k_attn5<<<2048, 128, 0, stream>>>(Qb, Kf, Vf, yb);
    // 7. out = y @ Wo + bo
    k_gemm_bt<<<dim3(EMB/128, MROWS/128), 256, 0, stream>>>(yb, Wot, out, MROWS, EMB, EMB, bo);
}